// Round 9
// baseline (178.171 us; speedup 1.0000x reference)
//
#include <hip/hip_runtime.h>

// EdgeConv on dense bipartite graph: A=256, U=1024, D=64.
// out[a,u] = edge@W3t - (relu(edge@W1b+c1[a]) + relu(edge@W2b+c2[u]))@W3b + s3[a] + s4[u]
// with c1 = ap_hid@W1t+b1, c2 = ue_hid@W2t+b2, s3 = ap_sum@W3b, s4 = ue_sum@W3b+b3.
//
// R11: kernel elimination. out splits as (e@W3t - t@W3b) + s3[a] + s4[u];
// the edge-dependent part is computed INSIDE pass1 (k_main), which already
// holds the edge A-frags and t in registers -- pass2's 64MB edge re-read,
// 64MB weight/c2/s4 traffic, and its whole latency-bound chain disappear.
// A trivially BW-bound k_add applies += s3[a]+s4[u] in-place afterwards.
// Kernels: k_prep -> k_main(1024) -> k_mid(320) -> k_add(2048).

#define A_N 256
#define U_N 1024

typedef short short8 __attribute__((ext_vector_type(8)));
typedef float f32x4 __attribute__((ext_vector_type(4)));

__device__ __forceinline__ unsigned short f2bf(float f) {
  unsigned int u = __float_as_uint(f);
  return (unsigned short)((u + 0x7FFFu + ((u >> 16) & 1u)) >> 16);  // RNE
}

__device__ __forceinline__ f32x4 mfma16(short8 a, short8 b, f32x4 c) {
  return __builtin_amdgcn_mfma_f32_16x16x32_bf16(a, b, c, 0, 0, 0);
}

__device__ __forceinline__ void cvt16(const float4& e0, const float4& e1,
                                      const float4& e2, const float4& e3,
                                      short8& a0, short8& a1) {
  a0[0] = (short)f2bf(e0.x); a0[1] = (short)f2bf(e0.y);
  a0[2] = (short)f2bf(e0.z); a0[3] = (short)f2bf(e0.w);
  a0[4] = (short)f2bf(e1.x); a0[5] = (short)f2bf(e1.y);
  a0[6] = (short)f2bf(e1.z); a0[7] = (short)f2bf(e1.w);
  a1[0] = (short)f2bf(e2.x); a1[1] = (short)f2bf(e2.y);
  a1[2] = (short)f2bf(e2.z); a1[3] = (short)f2bf(e2.w);
  a1[4] = (short)f2bf(e3.x); a1[5] = (short)f2bf(e3.y);
  a1[6] = (short)f2bf(e3.z); a1[7] = (short)f2bf(e3.w);
}

__device__ __forceinline__ void rowmlp_row(const float* __restrict__ in,
                                           const float* __restrict__ W,
                                           const float* __restrict__ bias,
                                           float* __restrict__ out, int r, int lane) {
  float rv = in[r * 64 + lane];
  float acc = bias ? bias[lane] : 0.f;
#pragma unroll
  for (int k = 0; k < 64; k++) acc += __shfl(rv, k, 64) * W[k * 64 + lane];
  out[r * 64 + lane] = acc;
}

// Fused setup: build Wt (bf16, n-major, 4 sections), c1, c2.
// Wt rows 0-63: W1_bot^T, 64-127: W2_bot^T, 128-191: W3_top^T, 192-255: W3_bot^T
__global__ __launch_bounds__(256) void k_prep(
    const float* __restrict__ ap_hid, const float* __restrict__ ue_hid,
    const float* __restrict__ W1, const float* __restrict__ b1,
    const float* __restrict__ W2, const float* __restrict__ b2,
    const float* __restrict__ W3, unsigned short* __restrict__ Wt,
    float* __restrict__ c1, float* __restrict__ c2) {
  int bx = blockIdx.x, tid = threadIdx.x;
  if (bx < 64) {
    int idx = bx * 256 + tid;  // 16384 total
    int r = idx >> 6, k = idx & 63;
    int sec = r >> 6, d = r & 63;
    float v;
    if (sec == 0)      v = W1[(64 + k) * 64 + d];
    else if (sec == 1) v = W2[(64 + k) * 64 + d];
    else if (sec == 2) v = W3[k * 64 + d];
    else               v = W3[(64 + k) * 64 + d];
    Wt[r * 64 + k] = f2bf(v);
  } else if (bx < 128) {
    int r = (bx - 64) * 4 + (tid >> 6);
    rowmlp_row(ap_hid, W1, b1, c1, r, tid & 63);
  } else {  // bx in [128, 384)
    int r = (bx - 128) * 4 + (tid >> 6);
    rowmlp_row(ue_hid, W2, b2, c2, r, tid & 63);
  }
}

// Main: pass1 + edge-part of out, fused. Per block (chunk of 4 a's x 64-u
// panel), per a-slice: P1 (->ap partial via LDS accumulator), P2 (->ue
// partial in regs), keep t = relu(P1+c1)+relu(P2+c2) per-element, P3, and
// write out = P3 - t@W3b (s3/s4 added later by k_add). Edge+c1 for the next
// slice register-prefetched (R6 pipeline). t transposes through wave-private
// LDS rows (DS in-order per wave, no barrier).
__global__ __launch_bounds__(256) void k_main(
    const float* __restrict__ edge, const unsigned short* __restrict__ Wt,
    const float* __restrict__ c1, const float* __restrict__ c2,
    float* __restrict__ ap_part, float* __restrict__ ue_part,
    float* __restrict__ out) {
  __shared__ float ap_l[4 * 64];            // [slice c][d]
  __shared__ unsigned short t_lds[64 * 72];
  int tid = threadIdx.x, lane = tid & 63, w = tid >> 6;
  int fr = lane & 15, fq = lane >> 4;
  int chunk = blockIdx.x >> 4;
  int panel = blockIdx.x & 15;
  int a0 = chunk * 4;
  int u0 = panel * 64;
  int urow = u0 + w * 16 + fr;
  const float* erow = edge + urow * 64 + fq * 8;  // + a*65536

  ap_l[tid] = 0.f;
  __syncthreads();

  // loop-invariant B-fragments: W1b (0-3), W2b (4-7), W3t, W3b -- all in regs
  short8 bw[8][2], w3t[4][2], w3b[4][2];
#pragma unroll
  for (int nt = 0; nt < 8; nt++)
#pragma unroll
    for (int ks = 0; ks < 2; ks++)
      bw[nt][ks] = *(const short8*)(Wt + (nt * 16 + fr) * 64 + ks * 32 + fq * 8);
#pragma unroll
  for (int j = 0; j < 4; j++)
#pragma unroll
    for (int ks = 0; ks < 2; ks++) {
      w3t[j][ks] = *(const short8*)(Wt + (128 + j * 16 + fr) * 64 + ks * 32 + fq * 8);
      w3b[j][ks] = *(const short8*)(Wt + (192 + j * 16 + fr) * 64 + ks * 32 + fq * 8);
    }

  float c2v[4][4];
#pragma unroll
  for (int j = 0; j < 4; j++)
#pragma unroll
    for (int i = 0; i < 4; i++)
      c2v[j][i] = c2[(u0 + w * 16 + fq * 4 + i) * 64 + j * 16 + fr];

  float ureg[4][4];
#pragma unroll
  for (int j = 0; j < 4; j++)
#pragma unroll
    for (int i = 0; i < 4; i++) ureg[j][i] = 0.f;

  // prefetch slice a0
  const float* p0 = erow + a0 * 65536;
  float4 e0 = *(const float4*)(p0);
  float4 e1 = *(const float4*)(p0 + 4);
  float4 e2 = *(const float4*)(p0 + 32);
  float4 e3 = *(const float4*)(p0 + 36);
  float c1v[4];
#pragma unroll
  for (int j = 0; j < 4; j++) c1v[j] = c1[a0 * 64 + j * 16 + fr];

  for (int c = 0; c < 4; c++) {
    int a = a0 + c;
    float4 n0, n1, n2, n3;
    float nc1[4];
    if (c < 3) {
      const float* np = erow + (a + 1) * 65536;
      n0 = *(const float4*)(np);
      n1 = *(const float4*)(np + 4);
      n2 = *(const float4*)(np + 32);
      n3 = *(const float4*)(np + 36);
#pragma unroll
      for (int j = 0; j < 4; j++) nc1[j] = c1[(a + 1) * 64 + j * 16 + fr];
    }
    short8 af0, af1;
    cvt16(e0, e1, e2, e3, af0, af1);

    f32x4 accP3[4];
#pragma unroll
    for (int j = 0; j < 4; j++) {
      // P1: tv1 kept per-element; row-reduce -> LDS accumulator (cross-wave)
      f32x4 a1 = {0.f, 0.f, 0.f, 0.f};
      a1 = mfma16(af0, bw[j][0], a1);
      a1 = mfma16(af1, bw[j][1], a1);
      float cv = c1v[j];
      float tv1[4];
      tv1[0] = fmaxf(a1[0] + cv, 0.f);
      tv1[1] = fmaxf(a1[1] + cv, 0.f);
      tv1[2] = fmaxf(a1[2] + cv, 0.f);
      tv1[3] = fmaxf(a1[3] + cv, 0.f);
      float rs = tv1[0] + tv1[1] + tv1[2] + tv1[3];
      rs += __shfl_xor(rs, 16, 64);
      rs += __shfl_xor(rs, 32, 64);
      if (lane < 16) atomicAdd(&ap_l[c * 64 + j * 16 + lane], rs);  // LDS atomic
      // P2: ue accumulation + t = tv1 + relu(P2+c2) -> wave-private t_lds
      f32x4 a2 = {0.f, 0.f, 0.f, 0.f};
      a2 = mfma16(af0, bw[4 + j][0], a2);
      a2 = mfma16(af1, bw[4 + j][1], a2);
#pragma unroll
      for (int i = 0; i < 4; i++) {
        float r2 = fmaxf(a2[i] + c2v[j][i], 0.f);
        ureg[j][i] += r2;
        t_lds[(w * 16 + fq * 4 + i) * 72 + j * 16 + fr] = f2bf(tv1[i] + r2);
      }
      // P3: e@W3t
      f32x4 p3 = {0.f, 0.f, 0.f, 0.f};
      p3 = mfma16(af0, w3t[j][0], p3);
      p3 = mfma16(af1, w3t[j][1], p3);
      accP3[j] = p3;
    }
    // GEMM2: A = t (this wave's own rows; DS in-order per wave, no barrier)
    short8 tf0 = *(const short8*)&t_lds[(w * 16 + fr) * 72 + fq * 8];
    short8 tf1 = *(const short8*)&t_lds[(w * 16 + fr) * 72 + 32 + fq * 8];
#pragma unroll
    for (int j = 0; j < 4; j++) {
      f32x4 acc = {0.f, 0.f, 0.f, 0.f};
      acc = mfma16(tf0, w3b[j][0], acc);
      acc = mfma16(tf1, w3b[j][1], acc);
#pragma unroll
      for (int i = 0; i < 4; i++) {
        int u = u0 + w * 16 + fq * 4 + i;
        out[(a * 1024 + u) * 64 + j * 16 + fr] = accP3[j][i] - acc[i];
      }
    }
    if (c < 3) {
      e0 = n0; e1 = n1; e2 = n2; e3 = n3;
#pragma unroll
      for (int j = 0; j < 4; j++) c1v[j] = nc1[j];
    }
  }
  // ue partials: plain stores (this block is the unique writer for (chunk, u))
#pragma unroll
  for (int j = 0; j < 4; j++)
#pragma unroll
    for (int i = 0; i < 4; i++)
      ue_part[(chunk * 1024 + u0 + w * 16 + fq * 4 + i) * 64 + j * 16 + fr] =
          ureg[j][i];
  __syncthreads();
  // ap partials: one per thread (this block is the unique writer for (panel, a))
  ap_part[(panel * 256 + a0 + w) * 64 + lane] = ap_l[tid];
}

// Mid (R6 form): reduce partials -> row sums -> fused row-MLP:
// s3 = ap_sum@W3b, s4 = ue_sum@W3b + b3.  320 blocks x 4 rows.
__global__ __launch_bounds__(256) void k_mid(
    const float* __restrict__ ap_part, const float* __restrict__ ue_part,
    const float* __restrict__ W3, const float* __restrict__ b3,
    float* __restrict__ s3, float* __restrict__ s4) {
  int bx = blockIdx.x, tid = threadIdx.x, lane = tid & 63;
  const float* W3b = W3 + 4096;
  if (bx < 64) {
    int r = bx * 4 + (tid >> 6);
    float v = 0.f;
#pragma unroll
    for (int p = 0; p < 16; p++) v += ap_part[(p * 256 + r) * 64 + lane];
    float acc = 0.f;
#pragma unroll
    for (int k = 0; k < 64; k++) acc += __shfl(v, k, 64) * W3b[k * 64 + lane];
    s3[r * 64 + lane] = acc;
  } else {  // bx in [64, 320)
    int r = (bx - 64) * 4 + (tid >> 6);
    float v = 0.f;
#pragma unroll
    for (int p = 0; p < 64; p++) v += ue_part[(p * 1024 + r) * 64 + lane];
    float acc = b3[lane];
#pragma unroll
    for (int k = 0; k < 64; k++) acc += __shfl(v, k, 64) * W3b[k * 64 + lane];
    s4[r * 64 + lane] = acc;
  }
}

// Add: out[a,u,:] += s3[a,:] + s4[u,:], in place. float4 per lane, 8-step
// grid-stride; s3 (64KB) / s4 (256KB) are L2-resident broadcasts.
__global__ __launch_bounds__(256) void k_add(
    float* __restrict__ out, const float* __restrict__ s3,
    const float* __restrict__ s4) {
  int idx = blockIdx.x * 256 + threadIdx.x;  // float4 index base
#pragma unroll
  for (int it = 0; it < 8; it++) {
    int f = idx + it * 524288;               // 2048 blocks * 256 threads
    int a = f >> 14;                         // 16384 float4 per a
    int u = (f >> 4) & 1023;
    int q = f & 15;
    float4 v = *(float4*)&out[f * 4];
    float4 x = *(const float4*)&s3[a * 64 + q * 4];
    float4 y = *(const float4*)&s4[u * 64 + q * 4];
    v.x += x.x + y.x; v.y += x.y + y.y;
    v.z += x.z + y.z; v.w += x.w + y.w;
    *(float4*)&out[f * 4] = v;
  }
}

extern "C" void kernel_launch(void* const* d_in, const int* in_sizes, int n_in,
                              void* d_out, int out_size, void* d_ws, size_t ws_size,
                              hipStream_t stream) {
  const float* ap_hid = (const float*)d_in[0];
  const float* ue_hid = (const float*)d_in[1];
  const float* edge   = (const float*)d_in[2];
  const float* W1     = (const float*)d_in[3];
  const float* b1     = (const float*)d_in[4];
  const float* W2     = (const float*)d_in[5];
  const float* b2     = (const float*)d_in[6];
  const float* W3     = (const float*)d_in[7];
  const float* b3     = (const float*)d_in[8];
  float* out = (float*)d_out;

  char* ws = (char*)d_ws;
  unsigned short* Wt = (unsigned short*)ws;            //     32768 B
  float* c1      = (float*)(ws + 32768);               //     65536 B
  float* c2      = (float*)(ws + 98304);               //    262144 B
  float* s3      = (float*)(ws + 360448);              //     65536 B
  float* s4      = (float*)(ws + 425984);              //    262144 B
  float* ap_part = (float*)(ws + 688128);              //   4194304 B  [16][256][64]
  float* ue_part = (float*)(ws + 4882432);             //  16777216 B  [64][1024][64]

  k_prep<<<384, 256, 0, stream>>>(ap_hid, ue_hid, W1, b1, W2, b2, W3, Wt, c1, c2);
  k_main<<<1024, 256, 0, stream>>>(edge, Wt, c1, c2, ap_part, ue_part, out);
  k_mid<<<320, 256, 0, stream>>>(ap_part, ue_part, W3, b3, s3, s4);
  k_add<<<2048, 256, 0, stream>>>(out, s3, s4);
}